// Round 6
// baseline (289.969 us; speedup 1.0000x reference)
//
#include <hip/hip_runtime.h>
#include <math.h>

// Problem: inputs (32,64,64,64) BCHW fp32, codebook (1024,64) fp32
// out: [loss][q_st 8388608][perp][one-hot 134217728] fp32
typedef _Float16 half8 __attribute__((ext_vector_type(8)));
typedef float f32x4 __attribute__((ext_vector_type(4)));
typedef float f32x2 __attribute__((ext_vector_type(2)));

#define NBLK     1024
#define Q_OFF    1
#define PERP_OFF 8388609
#define OH_OFF   8388610
#define LOSS_N   8388608.0f

// ws byte layout:
// [0,4096)         cnorm (1024 f32)
// [4096,8192)      hist  (1024 int)
// [8192,12288)     partial (1024 f32)
// [16384,278528)   cb2: 64 tiles x 4KB; tile = 16 codes:
//                  [hi ks0 1KB | hi ks1 1KB | lo ks0 1KB | lo ks1 1KB],
//                  within each 1KB: code c (0..15) x 64B (dims g*8+i, g=0..3)
// [278528,802816)  idx (131072 int)
#define CB2_OFF_B 16384
#define IDX_OFF_W 69632   // 278528/4

__global__ __launch_bounds__(256) void k0_prep(const float* __restrict__ cb,
                                               float* __restrict__ cnorm,
                                               int* __restrict__ hist,
                                               char* __restrict__ cb2) {
  int k = blockIdx.x * 256 + threadIdx.x;   // grid=4 -> k in [0,1024)
  hist[k] = 0;
  const float* row = cb + (size_t)k * 64;
  const float4* r4 = (const float4*)row;
  float s = 0.f;
#pragma unroll
  for (int i = 0; i < 16; ++i) {
    float4 v = r4[i];
    s += v.x * v.x + v.y * v.y + v.z * v.z + v.w * v.w;
  }
  cnorm[k] = s;

  // fp16 hi/lo split, tile-contiguous layout for dense per-wave loads.
  int tile = k >> 4, c = k & 15;
  char* base = cb2 + tile * 4096;
#pragma unroll
  for (int d16 = 0; d16 < 8; ++d16) {
    half8 hh, ll;
#pragma unroll
    for (int i = 0; i < 8; ++i) {
      float v = row[d16 * 8 + i];
      _Float16 h = (_Float16)v;
      hh[i] = h;
      ll[i] = (_Float16)(v - (float)h);
    }
    int off = (d16 >> 2) * 1024 + c * 64 + (d16 & 3) * 16;  // ks | code | g
    *(half8*)(base + off) = hh;          // hi
    *(half8*)(base + 2048 + off) = ll;   // lo
  }
}

// Block = 384 thr (6 waves), 128 points (b fixed, 128-wide hw window).
// ROLE SPLIT: waves 0-3 compute (2 MFMA A-tiles each, B-frags straight from
// L2, NO stores inside the loop -> load waitcnts never wait on store drain);
// waves 4-5 stream the block's contiguous 512KB one-hot zero slab as pure
// nontemporal stores (no loads -> never throttled by anything but DRAM BW).
// dist = ||c||^2 - 2*x.c via 3-term fp16-split MFMA (exact-argmin vs fp32,
// verified rounds 4-5). The 1.0s are scattered by k3 afterwards.
__global__ __launch_bounds__(384, 2) void k1_main(
    const float* __restrict__ in, const float* __restrict__ cb,
    const char* __restrict__ cb2, const float* __restrict__ cnorm,
    int* __restrict__ hist, float* __restrict__ partial,
    int* __restrict__ idx, float* __restrict__ out) {
  __shared__ int bestk_s[128];
  __shared__ float red[256];

  const int tid = threadIdx.x;
  const int bid = blockIdx.x;
  const int b = bid >> 5;
  const int hw0 = (bid & 31) << 7;

  if (tid >= 256) {
    // ---- fill waves (4,5): 512KB contiguous NT zero stream ----
    const int f = tid - 256;            // 0..127
    f32x2* ohz = (f32x2*)(out + OH_OFF) + (size_t)bid * 65536 + f;
    const f32x2 z2 = {0.f, 0.f};
#pragma unroll 8
    for (int i = 0; i < 512; ++i)
      __builtin_nontemporal_store(z2, &ohz[(size_t)i * 128]);
  } else {
    // ---- compute waves (0-3): verbatim R5 structure, stores removed ----
    const int w = tid >> 6, l = tid & 63, q = l & 15, g = l >> 4;

    // A fragments: 2 point-tiles x 2 ksteps, fp16 hi/lo.
    // lane holds A[row=q][k = g*8+i (+32 for ks=1)]
    half8 ah[2][2], al[2][2];
    {
      const float* xb = in + ((size_t)b << 18);
#pragma unroll
      for (int a = 0; a < 2; ++a) {
        const int hw = hw0 + w * 32 + a * 16 + q;
#pragma unroll
        for (int ks = 0; ks < 2; ++ks) {
#pragma unroll
          for (int i = 0; i < 8; ++i) {
            float v = xb[((size_t)(ks * 32 + g * 8 + i) << 12) + hw];
            _Float16 h = (_Float16)v;
            ah[a][ks][i] = h;
            al[a][ks][i] = (_Float16)(v - (float)h);
          }
        }
      }
    }

    float bd0[4], bd1[4];
    int bk0[4], bk1[4];
#pragma unroll
    for (int j = 0; j < 4; ++j) { bd0[j] = bd1[j] = 3.4e38f; bk0[j] = bk1[j] = 0; }

    const int boff = q * 64 + g * 16;            // dense 1KB per wave-load

    for (int tb = 0; tb < 64; ++tb) {
      const char* tbase = cb2 + tb * 4096 + boff;
      half8 bh0 = *(const half8*)(tbase);
      half8 bh1 = *(const half8*)(tbase + 1024);
      half8 bl0 = *(const half8*)(tbase + 2048);
      half8 bl1 = *(const half8*)(tbase + 3072);
      const int code = tb * 16 + q;
      const float cn = cnorm[code];
      const f32x4 z = {0.f, 0.f, 0.f, 0.f};
      // a = 0: dot = xh.ch + xl.ch + xh.cl  (two 3-chains for ILP)
      f32x4 s = __builtin_amdgcn_mfma_f32_16x16x32_f16(ah[0][0], bh0, z, 0, 0, 0);
      s = __builtin_amdgcn_mfma_f32_16x16x32_f16(al[0][0], bh0, s, 0, 0, 0);
      s = __builtin_amdgcn_mfma_f32_16x16x32_f16(ah[0][0], bl0, s, 0, 0, 0);
      f32x4 t = __builtin_amdgcn_mfma_f32_16x16x32_f16(ah[0][1], bh1, z, 0, 0, 0);
      t = __builtin_amdgcn_mfma_f32_16x16x32_f16(al[0][1], bh1, t, 0, 0, 0);
      t = __builtin_amdgcn_mfma_f32_16x16x32_f16(ah[0][1], bl1, t, 0, 0, 0);
      s = s + t;
#pragma unroll
      for (int j = 0; j < 4; ++j) {
        float d = fmaf(-2.f, s[j], cn);
        if (d < bd0[j]) { bd0[j] = d; bk0[j] = code; }
      }
      // a = 1
      f32x4 u = __builtin_amdgcn_mfma_f32_16x16x32_f16(ah[1][0], bh0, z, 0, 0, 0);
      u = __builtin_amdgcn_mfma_f32_16x16x32_f16(al[1][0], bh0, u, 0, 0, 0);
      u = __builtin_amdgcn_mfma_f32_16x16x32_f16(ah[1][0], bl0, u, 0, 0, 0);
      f32x4 v = __builtin_amdgcn_mfma_f32_16x16x32_f16(ah[1][1], bh1, z, 0, 0, 0);
      v = __builtin_amdgcn_mfma_f32_16x16x32_f16(al[1][1], bh1, v, 0, 0, 0);
      v = __builtin_amdgcn_mfma_f32_16x16x32_f16(ah[1][1], bl1, v, 0, 0, 0);
      u = u + v;
#pragma unroll
      for (int j = 0; j < 4; ++j) {
        float d = fmaf(-2.f, u[j], cn);
        if (d < bd1[j]) { bd1[j] = d; bk1[j] = code; }
      }
    }

    // Butterfly argmin across the 16 code-residues (q = lane&15).
    // Equal distances -> lower code index (reference: first-index argmax).
#pragma unroll
    for (int m = 1; m < 16; m <<= 1) {
#pragma unroll
      for (int j = 0; j < 4; ++j) {
        float od = __shfl_xor(bd0[j], m, 64);
        int ok = __shfl_xor(bk0[j], m, 64);
        if (od < bd0[j] || (od == bd0[j] && ok < bk0[j])) { bd0[j] = od; bk0[j] = ok; }
        od = __shfl_xor(bd1[j], m, 64);
        ok = __shfl_xor(bk1[j], m, 64);
        if (od < bd1[j] || (od == bd1[j] && ok < bk1[j])) { bd1[j] = od; bk1[j] = ok; }
      }
    }
    if (q == 0) {
#pragma unroll
      for (int j = 0; j < 4; ++j) {
        bestk_s[w * 32 + g * 4 + j] = bk0[j];          // a=0 tile
        bestk_s[w * 32 + 16 + g * 4 + j] = bk1[j];     // a=1 tile
      }
    }
  }
  __syncthreads();

  // ---- Epilogue: idx, hist, q_st, loss (first 256 threads work) ----
  float lsum = 0.f;
  if (tid < 256) {
    const int p = tid & 127, hf = tid >> 7;
    const int kq = bestk_s[p];
    if (hf == 0) {
      idx[bid * 128 + p] = kq;
      atomicAdd(&hist[kq], 1);   // integer: deterministic
    }
    const float* xb = in + ((size_t)b << 18) + hw0 + p;
    float* yb = out + Q_OFF + ((size_t)b << 18) + hw0 + p;
    const float* qrow = cb + (size_t)kq * 64;
#pragma unroll
    for (int c = 0; c < 32; ++c) {
      const int cc = hf * 32 + c;
      float x = xb[(size_t)cc << 12];
      float f = qrow[cc] - x;
      lsum += f * f;
      yb[(size_t)cc << 12] = x + f;   // fl(x + fl(q-x)) as reference
    }
  }
  if (tid < 256) red[tid] = lsum;
  __syncthreads();
#pragma unroll
  for (int sft = 128; sft > 0; sft >>= 1) {
    if (tid < sft) red[tid] += red[tid + sft];
    __syncthreads();
  }
  if (tid == 0) partial[bid] = red[0];
}

__global__ __launch_bounds__(1024) void k2_finalize(const int* __restrict__ hist,
                                                    const float* __restrict__ partial,
                                                    float* __restrict__ out) {
  __shared__ float red[1024];
  int tid = threadIdx.x;

  // loss = 0.25 * mean((q-x)^2)
  red[tid] = partial[tid];
  __syncthreads();
  for (int s = 512; s > 0; s >>= 1) {
    if (tid < s) red[tid] += red[tid + s];
    __syncthreads();
  }
  if (tid == 0) out[0] = 0.25f * (red[0] / LOSS_N);
  __syncthreads();

  // perplexity = exp(-sum p*log(p+1e-10)), p = count / 2^17 (exact)
  float pr = (float)hist[tid] * (1.0f / 131072.0f);
  red[tid] = pr * logf(pr + 1e-10f);
  __syncthreads();
  for (int s = 512; s > 0; s >>= 1) {
    if (tid < s) red[tid] += red[tid + s];
    __syncthreads();
  }
  if (tid == 0) out[PERP_OFF] = expf(-red[0]);
}

__global__ __launch_bounds__(256) void k3_scatter(const int* __restrict__ idx,
                                                  float* __restrict__ out) {
  int n = blockIdx.x * 256 + threadIdx.x;
  int k = idx[n];
  int b = n >> 12;
  int pos = n & 4095;
  out[OH_OFF + ((((size_t)b << 10) + (size_t)k) << 12) + pos] = 1.0f;
}

extern "C" void kernel_launch(void* const* d_in, const int* in_sizes, int n_in,
                              void* d_out, int out_size, void* d_ws, size_t ws_size,
                              hipStream_t stream) {
  const float* in = (const float*)d_in[0];
  const float* cb = (const float*)d_in[1];
  float* out = (float*)d_out;

  float* cnorm   = (float*)d_ws;
  int*   hist    = (int*)d_ws + 1024;
  float* partial = (float*)d_ws + 2048;
  char*  cb2b    = (char*)d_ws + CB2_OFF_B;
  int*   idx     = (int*)d_ws + IDX_OFF_W;

  k0_prep<<<4, 256, 0, stream>>>(cb, cnorm, hist, cb2b);
  k1_main<<<NBLK, 384, 0, stream>>>(in, cb, cb2b, cnorm, hist, partial, idx, out);
  k2_finalize<<<1, 1024, 0, stream>>>(hist, partial, out);
  k3_scatter<<<512, 256, 0, stream>>>(idx, out);
}

// Round 7
// 223.021 us; speedup vs baseline: 1.3002x; 1.3002x over previous
//
#include <hip/hip_runtime.h>
#include <math.h>

// Problem: inputs (32,64,64,64) BCHW fp32, codebook (1024,64) fp32
// out: [loss][q_st 8388608][perp][one-hot 134217728] fp32
typedef _Float16 half8 __attribute__((ext_vector_type(8)));
typedef float f32x4 __attribute__((ext_vector_type(4)));

#define NBLK_TOT 1536          // 1024 compute + 512 fill, interleaved mod 3
#define Q_OFF    1
#define PERP_OFF 8388609
#define OH_OFF   8388610
#define LOSS_N   8388608.0f
// one-hot region floats [8388610, 142606338); 16B-aligned f4 span starts at
// float 8388612, 33554431 float4s; stray floats: 8388610,8388611 (head),
// 142606336,142606337 (tail).
#define OH_F4_BASE 8388612
#define OH_NF4     33554431

// ws byte layout:
// [0,4096)         cnorm (1024 f32)
// [4096,8192)      hist  (1024 int)
// [8192,12288)     partial (1024 f32)
// [16384,278528)   cb2: 64 tiles x 4KB; tile = 16 codes:
//                  [hi ks0 1KB | hi ks1 1KB | lo ks0 1KB | lo ks1 1KB],
//                  within each 1KB: code c (0..15) x 64B (dims g*8+i, g=0..3)
// [278528,802816)  idx (131072 int)
#define CB2_OFF_B 16384
#define IDX_OFF_W 69632   // 278528/4

__global__ __launch_bounds__(256) void k0_prep(const float* __restrict__ cb,
                                               float* __restrict__ cnorm,
                                               int* __restrict__ hist,
                                               char* __restrict__ cb2) {
  int k = blockIdx.x * 256 + threadIdx.x;   // grid=4 -> k in [0,1024)
  hist[k] = 0;
  const float* row = cb + (size_t)k * 64;
  const float4* r4 = (const float4*)row;
  float s = 0.f;
#pragma unroll
  for (int i = 0; i < 16; ++i) {
    float4 v = r4[i];
    s += v.x * v.x + v.y * v.y + v.z * v.z + v.w * v.w;
  }
  cnorm[k] = s;

  // fp16 hi/lo split, tile-contiguous layout for dense per-wave loads.
  int tile = k >> 4, c = k & 15;
  char* base = cb2 + tile * 4096;
#pragma unroll
  for (int d16 = 0; d16 < 8; ++d16) {
    half8 hh, ll;
#pragma unroll
    for (int i = 0; i < 8; ++i) {
      float v = row[d16 * 8 + i];
      _Float16 h = (_Float16)v;
      hh[i] = h;
      ll[i] = (_Float16)(v - (float)h);
    }
    int off = (d16 >> 2) * 1024 + c * 64 + (d16 & 3) * 16;  // ks | code | g
    *(half8*)(base + off) = hh;          // hi
    *(half8*)(base + 2048 + off) = ll;   // lo
  }
}

// Heterogeneous grid, 1536 blocks x 256 thr:
//   bid%3==2 -> FILL block: streams 1MB of the one-hot zero region as plain
//               cached float4 stores (the fillBufferAligned-proven 6.8TB/s
//               path). No barriers, retires independently.
//   else     -> COMPUTE block ci=(bid/3)*2+bid%3: verbatim R5 MFMA structure
//               (2 A-tiles/wave, B-frags from L2, no stores in the loop).
// Interleaving mod 3 puts both roles on every CU from dispatch -> overlap
// without any intra-block coupling. 1.0s scattered by k3 afterwards.
__global__ __launch_bounds__(256, 4) void k1_main(
    const float* __restrict__ in, const float* __restrict__ cb,
    const char* __restrict__ cb2, const float* __restrict__ cnorm,
    int* __restrict__ hist, float* __restrict__ partial,
    int* __restrict__ idx, float* __restrict__ out) {
  __shared__ int bestk_s[128];
  __shared__ float red[256];

  const int tid = threadIdx.x;
  const int bid = blockIdx.x;
  const int r3 = bid % 3;

  if (r3 == 2) {
    // ---- FILL block: 1MB contiguous, plain float4 stores ----
    const int fi = bid / 3;              // 0..511
    float4* base = (float4*)(out + OH_F4_BASE);
    const float4 z4 = make_float4(0.f, 0.f, 0.f, 0.f);
    const size_t b0 = (size_t)fi * 65536 + tid;
    if (fi < 511) {
#pragma unroll 8
      for (int i = 0; i < 256; ++i) base[b0 + (size_t)i * 256] = z4;
    } else {
#pragma unroll 8
      for (int i = 0; i < 256; ++i) {
        size_t i4 = b0 + (size_t)i * 256;
        if (i4 < OH_NF4) base[i4] = z4;
      }
      if (tid == 0) {   // stray head/tail floats of the misaligned region
        out[OH_OFF] = 0.f; out[OH_OFF + 1] = 0.f;
        out[OH_F4_BASE + 4 * (size_t)OH_NF4] = 0.f;
        out[OH_F4_BASE + 4 * (size_t)OH_NF4 + 1] = 0.f;
      }
    }
    return;
  }

  // ---- COMPUTE block ----
  const int ci = (bid / 3) * 2 + r3;     // 0..1023
  const int b = ci >> 5;
  const int hw0 = (ci & 31) << 7;
  const int w = tid >> 6, l = tid & 63, q = l & 15, g = l >> 4;

  // A fragments: 2 point-tiles x 2 ksteps, fp16 hi/lo.
  // lane holds A[row=q][k = g*8+i (+32 for ks=1)]
  half8 ah[2][2], al[2][2];
  {
    const float* xb = in + ((size_t)b << 18);
#pragma unroll
    for (int a = 0; a < 2; ++a) {
      const int hw = hw0 + w * 32 + a * 16 + q;
#pragma unroll
      for (int ks = 0; ks < 2; ++ks) {
#pragma unroll
        for (int i = 0; i < 8; ++i) {
          float v = xb[((size_t)(ks * 32 + g * 8 + i) << 12) + hw];
          _Float16 h = (_Float16)v;
          ah[a][ks][i] = h;
          al[a][ks][i] = (_Float16)(v - (float)h);
        }
      }
    }
  }

  float bd0[4], bd1[4];
  int bk0[4], bk1[4];
#pragma unroll
  for (int j = 0; j < 4; ++j) { bd0[j] = bd1[j] = 3.4e38f; bk0[j] = bk1[j] = 0; }

  const int boff = q * 64 + g * 16;            // dense 1KB per wave-load

  for (int tb = 0; tb < 64; ++tb) {
    const char* tbase = cb2 + tb * 4096 + boff;
    half8 bh0 = *(const half8*)(tbase);
    half8 bh1 = *(const half8*)(tbase + 1024);
    half8 bl0 = *(const half8*)(tbase + 2048);
    half8 bl1 = *(const half8*)(tbase + 3072);
    const int code = tb * 16 + q;
    const float cn = cnorm[code];
    const f32x4 z = {0.f, 0.f, 0.f, 0.f};
    // a = 0: dot = xh.ch + xl.ch + xh.cl  (two 3-chains for ILP)
    f32x4 s = __builtin_amdgcn_mfma_f32_16x16x32_f16(ah[0][0], bh0, z, 0, 0, 0);
    s = __builtin_amdgcn_mfma_f32_16x16x32_f16(al[0][0], bh0, s, 0, 0, 0);
    s = __builtin_amdgcn_mfma_f32_16x16x32_f16(ah[0][0], bl0, s, 0, 0, 0);
    f32x4 t = __builtin_amdgcn_mfma_f32_16x16x32_f16(ah[0][1], bh1, z, 0, 0, 0);
    t = __builtin_amdgcn_mfma_f32_16x16x32_f16(al[0][1], bh1, t, 0, 0, 0);
    t = __builtin_amdgcn_mfma_f32_16x16x32_f16(ah[0][1], bl1, t, 0, 0, 0);
    s = s + t;
#pragma unroll
    for (int j = 0; j < 4; ++j) {
      float d = fmaf(-2.f, s[j], cn);
      if (d < bd0[j]) { bd0[j] = d; bk0[j] = code; }
    }
    // a = 1
    f32x4 u = __builtin_amdgcn_mfma_f32_16x16x32_f16(ah[1][0], bh0, z, 0, 0, 0);
    u = __builtin_amdgcn_mfma_f32_16x16x32_f16(al[1][0], bh0, u, 0, 0, 0);
    u = __builtin_amdgcn_mfma_f32_16x16x32_f16(ah[1][0], bl0, u, 0, 0, 0);
    f32x4 v = __builtin_amdgcn_mfma_f32_16x16x32_f16(ah[1][1], bh1, z, 0, 0, 0);
    v = __builtin_amdgcn_mfma_f32_16x16x32_f16(al[1][1], bh1, v, 0, 0, 0);
    v = __builtin_amdgcn_mfma_f32_16x16x32_f16(ah[1][1], bl1, v, 0, 0, 0);
    u = u + v;
#pragma unroll
    for (int j = 0; j < 4; ++j) {
      float d = fmaf(-2.f, u[j], cn);
      if (d < bd1[j]) { bd1[j] = d; bk1[j] = code; }
    }
  }

  // Butterfly argmin across the 16 code-residues (q = lane&15).
  // Equal distances -> lower code index (reference: first-index argmax).
#pragma unroll
  for (int m = 1; m < 16; m <<= 1) {
#pragma unroll
    for (int j = 0; j < 4; ++j) {
      float od = __shfl_xor(bd0[j], m, 64);
      int ok = __shfl_xor(bk0[j], m, 64);
      if (od < bd0[j] || (od == bd0[j] && ok < bk0[j])) { bd0[j] = od; bk0[j] = ok; }
      od = __shfl_xor(bd1[j], m, 64);
      ok = __shfl_xor(bk1[j], m, 64);
      if (od < bd1[j] || (od == bd1[j] && ok < bk1[j])) { bd1[j] = od; bk1[j] = ok; }
    }
  }
  if (q == 0) {
#pragma unroll
    for (int j = 0; j < 4; ++j) {
      bestk_s[w * 32 + g * 4 + j] = bk0[j];          // a=0 tile
      bestk_s[w * 32 + 16 + g * 4 + j] = bk1[j];     // a=1 tile
    }
  }
  __syncthreads();

  // ---- Epilogue: idx, hist, q_st, loss ----
  const int p = tid & 127, hf = tid >> 7;
  const int kq = bestk_s[p];
  if (hf == 0) {
    idx[ci * 128 + p] = kq;
    atomicAdd(&hist[kq], 1);   // integer: deterministic
  }
  float lsum = 0.f;
  {
    const float* xb = in + ((size_t)b << 18) + hw0 + p;
    float* yb = out + Q_OFF + ((size_t)b << 18) + hw0 + p;
    const float* qrow = cb + (size_t)kq * 64;
#pragma unroll
    for (int c = 0; c < 32; ++c) {
      const int cc = hf * 32 + c;
      float x = xb[(size_t)cc << 12];
      float f = qrow[cc] - x;
      lsum += f * f;
      yb[(size_t)cc << 12] = x + f;   // fl(x + fl(q-x)) as reference
    }
  }
  red[tid] = lsum;
  __syncthreads();
#pragma unroll
  for (int sft = 128; sft > 0; sft >>= 1) {
    if (tid < sft) red[tid] += red[tid + sft];
    __syncthreads();
  }
  if (tid == 0) partial[ci] = red[0];
}

__global__ __launch_bounds__(1024) void k2_finalize(const int* __restrict__ hist,
                                                    const float* __restrict__ partial,
                                                    float* __restrict__ out) {
  __shared__ float red[1024];
  int tid = threadIdx.x;

  // loss = 0.25 * mean((q-x)^2)
  red[tid] = partial[tid];
  __syncthreads();
  for (int s = 512; s > 0; s >>= 1) {
    if (tid < s) red[tid] += red[tid + s];
    __syncthreads();
  }
  if (tid == 0) out[0] = 0.25f * (red[0] / LOSS_N);
  __syncthreads();

  // perplexity = exp(-sum p*log(p+1e-10)), p = count / 2^17 (exact)
  float pr = (float)hist[tid] * (1.0f / 131072.0f);
  red[tid] = pr * logf(pr + 1e-10f);
  __syncthreads();
  for (int s = 512; s > 0; s >>= 1) {
    if (tid < s) red[tid] += red[tid + s];
    __syncthreads();
  }
  if (tid == 0) out[PERP_OFF] = expf(-red[0]);
}

__global__ __launch_bounds__(256) void k3_scatter(const int* __restrict__ idx,
                                                  float* __restrict__ out) {
  int n = blockIdx.x * 256 + threadIdx.x;
  int k = idx[n];
  int b = n >> 12;
  int pos = n & 4095;
  out[OH_OFF + ((((size_t)b << 10) + (size_t)k) << 12) + pos] = 1.0f;
}

extern "C" void kernel_launch(void* const* d_in, const int* in_sizes, int n_in,
                              void* d_out, int out_size, void* d_ws, size_t ws_size,
                              hipStream_t stream) {
  const float* in = (const float*)d_in[0];
  const float* cb = (const float*)d_in[1];
  float* out = (float*)d_out;

  float* cnorm   = (float*)d_ws;
  int*   hist    = (int*)d_ws + 1024;
  float* partial = (float*)d_ws + 2048;
  char*  cb2b    = (char*)d_ws + CB2_OFF_B;
  int*   idx     = (int*)d_ws + IDX_OFF_W;

  k0_prep<<<4, 256, 0, stream>>>(cb, cnorm, hist, cb2b);
  k1_main<<<NBLK_TOT, 256, 0, stream>>>(in, cb, cb2b, cnorm, hist, partial, idx, out);
  k2_finalize<<<1, 1024, 0, stream>>>(hist, partial, out);
  k3_scatter<<<512, 256, 0, stream>>>(idx, out);
}